// Round 2
// baseline (789.933 us; speedup 1.0000x reference)
//
#include <hip/hip_runtime.h>
#include <hip/hip_bf16.h>
#include <stdint.h>

typedef __attribute__((ext_vector_type(8)))  short    s16x8;
typedef __attribute__((ext_vector_type(16))) float    f32x16;
typedef __attribute__((ext_vector_type(4)))  float    f32x4;
typedef __attribute__((ext_vector_type(4)))  unsigned u32x4;

#define KSUB 8
// per-subnet ws blob (bytes):
//   0      W2' bf16 [64][64]  (scale-folded, XOR-swizzled)   8192
//   8192   W3'                                               8192
//   16384  W4'                                               8192
//   24576  W1pad bf16 [64][16] (cols 0..2 = s0*W1, col3 = s0*b1)  2048
//   26624  W5 bf16 [64]                                      128
//   26752  b2' f32[64]; 27008 b3'; 27264 b4'                 768
//   27520  pad                                               128
#define SUBSZ  27648
#define OFF_W  0
#define OFF_W1 24576
#define OFF_W5 26624
#define OFF_B  26752

#define LOG2E 1.4426950408889634f

__device__ __forceinline__ float fast_tanh(float z) {
  // tanh(z) = 1 - 2/(1+e^{2z}); e^{2z}=exp2(z*2*log2e). Inf-safe at both ends.
  float e = __builtin_amdgcn_exp2f(z * 2.885390081777927f);
  return __builtin_fmaf(-2.0f, __builtin_amdgcn_rcpf(e + 1.0f), 1.0f);
}

// round-to-nearest-even f32 -> bf16 bits (no NaN care needed in our domain)
__device__ __forceinline__ unsigned bf16r(float f) {
  unsigned u = __builtin_bit_cast(unsigned, f);
  return (u + 0x7fffu + ((u >> 16) & 1u)) >> 16;
}
__device__ __forceinline__ unsigned packbf(float lo, float hi) {
  return bf16r(lo) | (bf16r(hi) << 16);
}

__device__ __forceinline__ f32x16 mfma_bf16(s16x8 a, s16x8 b, f32x16 c) {
  return __builtin_amdgcn_mfma_f32_32x32x16_bf16(a, b, c, 0, 0, 0);
}

// C layout (32x32): col = lane&31 (=point), row j = (r&3)+8*(r>>2)+4*(lane>>5).
// Next-layer B-frag: lane needs act[k = 16kt+8g+2q(+1)][pt=lane&31].
// {Bu[kt*4+q], Bu[kt*4+q+2]} = permlane32_swap(pack(th[ra],th[ra+1]),
//   pack(th[rb],th[rb+1])), ra = ((2kt)&3)*4+2q, rb = ((2kt+1)&3)*4+2q,
//   source acc = acc0 for kt<2 else acc1. Verified for all kt,q,g.
__device__ __forceinline__ void epilogue(const f32x16& acc0, const f32x16& acc1,
                                         unsigned Bu[16]) {
#pragma unroll
  for (int kt = 0; kt < 4; ++kt) {
#pragma unroll
    for (int qq = 0; qq < 2; ++qq) {
      const int ra = ((2 * kt) & 3) * 4 + 2 * qq;
      const int rb = ((2 * kt + 1) & 3) * 4 + 2 * qq;
      float a0v, a1v, b0v, b1v;
      if (kt < 2) { a0v = acc0[ra]; a1v = acc0[ra + 1]; b0v = acc0[rb]; b1v = acc0[rb + 1]; }
      else        { a0v = acc1[ra]; a1v = acc1[ra + 1]; b0v = acc1[rb]; b1v = acc1[rb + 1]; }
      unsigned P0 = packbf(fast_tanh(a0v), fast_tanh(a1v));
      unsigned P1 = packbf(fast_tanh(b0v), fast_tanh(b1v));
      auto pr = __builtin_amdgcn_permlane32_swap(P0, P1, false, false);
      Bu[kt * 4 + qq]     = pr[0];
      Bu[kt * 4 + qq + 2] = pr[1];
    }
  }
}

__global__ void prep_weights(const float* __restrict__ W1, const float* __restrict__ b1,
                             const float* __restrict__ W2, const float* __restrict__ b2,
                             const float* __restrict__ W3, const float* __restrict__ b3,
                             const float* __restrict__ W4, const float* __restrict__ b4,
                             const float* __restrict__ W5, const float* __restrict__ scales,
                             char* __restrict__ ws) {
  const int sub = blockIdx.x;
  const int tid = threadIdx.x;
  char* dst = ws + sub * SUBSZ;
  const float s0 = scales[sub * 4 + 0], s1 = scales[sub * 4 + 1];
  const float s2 = scales[sub * 4 + 2], s3 = scales[sub * 4 + 3];
#pragma unroll
  for (int l = 0; l < 3; ++l) {
    const float* src = (l == 0) ? (W2 + sub * 4096) : (l == 1) ? (W3 + sub * 4096) : (W4 + sub * 4096);
    const float sc   = (l == 0) ? s1 : (l == 1) ? s2 : s3;
    __hip_bfloat16* d = (__hip_bfloat16*)(dst + OFF_W + l * 8192);
    for (int idx = tid; idx < 4096; idx += 256) {
      int row = idx >> 6, col = idx & 63;
      int de = row * 64 + (col ^ ((row & 7) << 3));   // XOR swizzle (16B granules)
      d[de] = __float2bfloat16(sc * src[idx]);
    }
  }
  { // W1pad [64][16]
    __hip_bfloat16* d = (__hip_bfloat16*)(dst + OFF_W1);
    for (int idx = tid; idx < 1024; idx += 256) {
      int row = idx >> 4, kc = idx & 15;
      float v = 0.f;
      if (kc < 3)       v = s0 * W1[sub * 192 + row * 3 + kc];
      else if (kc == 3) v = s0 * b1[sub * 64 + row];
      d[idx] = __float2bfloat16(v);
    }
  }
  if (tid < 64) {
    ((__hip_bfloat16*)(dst + OFF_W5))[tid] = __float2bfloat16(W5[sub * 64 + tid]);
    ((float*)(dst + OFF_B))[tid]        = s1 * b2[sub * 64 + tid];
    ((float*)(dst + OFF_B + 256))[tid]  = s2 * b3[sub * 64 + tid];
    ((float*)(dst + OFF_B + 512))[tid]  = s3 * b4[sub * 64 + tid];
  }
}

__global__ __launch_bounds__(256) void pinn_main(
    const float* __restrict__ X, const float* __restrict__ T,
    const char* __restrict__ ws, const float* __restrict__ centers,
    const float* __restrict__ lgam, const float* __restrict__ b5,
    float* __restrict__ out) {
  __shared__ __align__(16) char smem[SUBSZ];
  const int tid  = threadIdx.x;
  const int lane = tid & 63;
  const int wid  = tid >> 6;
  const int g    = lane >> 5;
  const int lpt  = lane & 31;
  const int p    = blockIdx.x * 128 + wid * 32 + lpt;

  const float x  = X[p];
  const float tt = T[p];
  float rr = x * 0.5f;
  rr = rr - floorf(rr);                                 // revolutions for v_sin/v_cos
  const float cpx = __builtin_amdgcn_cosf(rr);          // cos(pi*x)
  const float spx = __builtin_amdgcn_sinf(rr);          // sin(pi*x)
  const float u0  = x * x * cpx;
  const float thT = fast_tanh(tt);

  // max over gating logits (stability; gamma=e^3~20 => raw exp underflows)
  float m = -1e30f;
#pragma unroll
  for (int i = 0; i < 8; ++i) {
    float gx = __builtin_amdgcn_exp2f(lgam[2 * i] * LOG2E);
    float gt = __builtin_amdgcn_exp2f(lgam[2 * i + 1] * LOG2E);
    float dx = x - centers[2 * i], dt = tt - centers[2 * i + 1];
    float lg = -(gx * dx * dx + gt * dt * dt);
    m = fmaxf(m, lg);
  }

  // layer-1 B fragment: act0 = [cos, sin, t, 1, 0...] ; only k<4 (half g=0) nonzero
  unsigned b00 = packbf(cpx, spx);
  unsigned b01 = packbf(tt, 1.0f);
  if (g) { b00 = 0u; b01 = 0u; }

  float uacc = 0.f, S = 0.f;

  for (int sub = 0; sub < KSUB; ++sub) {
    __syncthreads();
    const char* gb = ws + sub * SUBSZ;
    for (int ch = wid; ch < SUBSZ / 1024; ch += 4) {    // 27 KB blob -> LDS
      *(f32x4*)(smem + ch * 1024 + lane * 16) = *(const f32x4*)(gb + ch * 1024 + lane * 16);
    }
    __syncthreads();

    // gating weight for this subnet (recomputed to avoid runtime-indexed reg arrays)
    float gx = __builtin_amdgcn_exp2f(lgam[2 * sub] * LOG2E);
    float gt = __builtin_amdgcn_exp2f(lgam[2 * sub + 1] * LOG2E);
    float dx = x - centers[2 * sub], dtt = tt - centers[2 * sub + 1];
    float lg = -(gx * dx * dx + gt * dtt * dtt);
    float ei = __builtin_amdgcn_exp2f((lg - m) * LOG2E);

    // ---- layer 1 (K=16 padded, bias folded into col 3) ----
    f32x16 acc0, acc1;
#pragma unroll
    for (int r = 0; r < 16; ++r) { acc0[r] = 0.f; acc1[r] = 0.f; }
    s16x8 a0 = *(const s16x8*)(smem + OFF_W1 + lpt * 32 + g * 16);
    s16x8 a1 = *(const s16x8*)(smem + OFF_W1 + (32 + lpt) * 32 + g * 16);
    u32x4 blv; blv[0] = b00; blv[1] = b01; blv[2] = 0u; blv[3] = 0u;
    s16x8 bl1 = __builtin_bit_cast(s16x8, blv);
    acc0 = mfma_bf16(a0, bl1, acc0);
    acc1 = mfma_bf16(a1, bl1, acc1);
    unsigned Bu[16];
    epilogue(acc0, acc1, Bu);

    // ---- hidden layers 2..4 ----
    for (int l = 0; l < 3; ++l) {
      const float* bias = (const float*)(smem + OFF_B + l * 256);
#pragma unroll
      for (int rq = 0; rq < 4; ++rq) {                  // acc init = scaled bias
        f32x4 bv0 = *(const f32x4*)(bias + 8 * rq + 4 * g);
        f32x4 bv1 = *(const f32x4*)(bias + 32 + 8 * rq + 4 * g);
#pragma unroll
        for (int rr2 = 0; rr2 < 4; ++rr2) { acc0[4 * rq + rr2] = bv0[rr2]; acc1[4 * rq + rr2] = bv1[rr2]; }
      }
      const char* wbase = smem + OFF_W + l * 8192;
#pragma unroll
      for (int kt = 0; kt < 4; ++kt) {
        const int coff = ((16 * kt + 8 * g) * 2) ^ ((lpt & 7) << 4);  // match prep swizzle
        s16x8 wa0 = *(const s16x8*)(wbase + lpt * 128 + coff);
        s16x8 wa1 = *(const s16x8*)(wbase + (32 + lpt) * 128 + coff);
        u32x4 bb; bb[0] = Bu[kt * 4]; bb[1] = Bu[kt * 4 + 1]; bb[2] = Bu[kt * 4 + 2]; bb[3] = Bu[kt * 4 + 3];
        s16x8 bf = __builtin_bit_cast(s16x8, bb);
        acc0 = mfma_bf16(wa0, bf, acc0);
        acc1 = mfma_bf16(wa1, bf, acc1);
      }
      epilogue(acc0, acc1, Bu);
    }

    // ---- layer 5: o = W5 . h4 (per-lane partial over its k-set, then cross-half add)
    float o = 0.f;
    const u32x4* w5p = (const u32x4*)(smem + OFF_W5);
#pragma unroll
    for (int kt = 0; kt < 4; ++kt) {
      u32x4 wv = w5p[2 * kt + g];
#pragma unroll
      for (int q = 0; q < 4; ++q) {
        unsigned w = wv[q], h = Bu[kt * 4 + q];
        float wlo = __builtin_bit_cast(float, w << 16);
        float whi = __builtin_bit_cast(float, w & 0xffff0000u);
        float hlo = __builtin_bit_cast(float, h << 16);
        float hhi = __builtin_bit_cast(float, h & 0xffff0000u);
        o = __builtin_fmaf(wlo, hlo, o);
        o = __builtin_fmaf(whi, hhi, o);
      }
    }
    o += __shfl_xor(o, 32);
    uacc = __builtin_fmaf(ei, o + b5[sub], uacc);
    S += ei;
  }

  float u = uacc * __builtin_amdgcn_rcpf(S);
  if (lane < 32) out[p] = thT * u + u0;
}

extern "C" void kernel_launch(void* const* d_in, const int* in_sizes, int n_in,
                              void* d_out, int out_size, void* d_ws, size_t ws_size,
                              hipStream_t stream) {
  const float* X   = (const float*)d_in[0];
  const float* T   = (const float*)d_in[1];
  const float* W1  = (const float*)d_in[2];
  const float* b1  = (const float*)d_in[3];
  const float* W2  = (const float*)d_in[4];
  const float* b2  = (const float*)d_in[5];
  const float* W3  = (const float*)d_in[6];
  const float* b3  = (const float*)d_in[7];
  const float* W4  = (const float*)d_in[8];
  const float* b4  = (const float*)d_in[9];
  const float* W5  = (const float*)d_in[10];
  const float* b5  = (const float*)d_in[11];
  const float* sc  = (const float*)d_in[12];
  const float* cen = (const float*)d_in[13];
  const float* lg  = (const float*)d_in[14];
  float* out = (float*)d_out;
  char*  ws  = (char*)d_ws;
  const int n = in_sizes[0];

  prep_weights<<<KSUB, 256, 0, stream>>>(W1, b1, W2, b2, W3, b3, W4, b4, W5, sc, ws);
  pinn_main<<<n / 128, 256, 0, stream>>>(X, T, ws, cen, lg, b5, out);
}

// Round 6
// 647.198 us; speedup vs baseline: 1.2205x; 1.2205x over previous
//
#include <hip/hip_runtime.h>
#include <hip/hip_bf16.h>
#include <stdint.h>

typedef __attribute__((ext_vector_type(8)))  short    s16x8;
typedef __attribute__((ext_vector_type(16))) float    f32x16;
typedef __attribute__((ext_vector_type(4)))  float    f32x4;
typedef __attribute__((ext_vector_type(4)))  unsigned u32x4;

#define KSUB 8
// per-subnet ws blob (bytes):
//   0      W2' bf16 [64][64]  (scale*2log2e folded, XOR-swizzled)   8192
//   8192   W3'                                                      8192
//   16384  W4'                                                      8192
//   24576  W1pad bf16 [64][16] (cols 0..2 = s0'*W1, col3 = s0'*b1)  2048
//   26624  W5 bf16 [64]                                             128
//   26752  b2' f32[64]; 27008 b3'; 27264 b4'  (all *2log2e*s)       768
//   27520  pad                                                      128
#define SUBSZ  27648
#define OFF_W  0
#define OFF_W1 24576
#define OFF_W5 26624
#define OFF_B  26752

#define LOG2E 1.4426950408889634f
#define TWOLOG2E 2.885390081777927f   // 2/ln2, folded into scales so MFMA acc = exp2 arg

__device__ __forceinline__ float fast_tanh(float z) {
  // tanh(z) = 1 - 2/(1+e^{2z}); inf-safe at both ends.
  float e = __builtin_amdgcn_exp2f(z * TWOLOG2E);
  return __builtin_fmaf(-2.0f, __builtin_amdgcn_rcpf(e + 1.0f), 1.0f);
}
// tanh where zeta = 2*log2e*z already (scale pre-folded into weights)
__device__ __forceinline__ float tanh_pre(float zeta) {
  float e = __builtin_amdgcn_exp2f(zeta);
  return __builtin_fmaf(-2.0f, __builtin_amdgcn_rcpf(e + 1.0f), 1.0f);
}

// pack two f32 -> bf16x2 with round-half-up: +0x8000 then one v_perm_b32.
__device__ __forceinline__ unsigned packbf(float lo, float hi) {
  unsigned ul = __builtin_bit_cast(unsigned, lo) + 0x8000u;
  unsigned uh = __builtin_bit_cast(unsigned, hi) + 0x8000u;
  return __builtin_amdgcn_perm(uh, ul, 0x07060302u);  // (uh&0xffff0000)|(ul>>16)
}

__device__ __forceinline__ f32x16 mfma_bf16(s16x8 a, s16x8 b, f32x16 c) {
  return __builtin_amdgcn_mfma_f32_32x32x16_bf16(a, b, c, 0, 0, 0);
}

// C layout (32x32): col = lane&31 (=point), row j = (r&3)+8*(r>>2)+4*(lane>>5).
// Next-layer B-frag: lane needs act[k = 16kt+8g+2q(+1)][pt=lane&31].
// {Bu[kt*4+q], Bu[kt*4+q+2]} = permlane32_swap(pack(th[ra],th[ra+1]),
//   pack(th[rb],th[rb+1])), ra=((2kt)&3)*4+2q, rb=((2kt+1)&3)*4+2q,
//   source acc = acc0 for kt<2 else acc1.
__device__ __forceinline__ void epilogue(const f32x16& acc0, const f32x16& acc1,
                                         unsigned Bu[16]) {
#pragma unroll
  for (int kt = 0; kt < 4; ++kt) {
#pragma unroll
    for (int qq = 0; qq < 2; ++qq) {
      const int ra = ((2 * kt) & 3) * 4 + 2 * qq;
      const int rb = ((2 * kt + 1) & 3) * 4 + 2 * qq;
      float a0v, a1v, b0v, b1v;
      if (kt < 2) { a0v = acc0[ra]; a1v = acc0[ra + 1]; b0v = acc0[rb]; b1v = acc0[rb + 1]; }
      else        { a0v = acc1[ra]; a1v = acc1[ra + 1]; b0v = acc1[rb]; b1v = acc1[rb + 1]; }
      unsigned P0 = packbf(tanh_pre(a0v), tanh_pre(a1v));
      unsigned P1 = packbf(tanh_pre(b0v), tanh_pre(b1v));
      auto pr = __builtin_amdgcn_permlane32_swap(P0, P1, false, false);
      Bu[kt * 4 + qq]     = pr[0];
      Bu[kt * 4 + qq + 2] = pr[1];
    }
  }
}

__global__ void prep_weights(const float* __restrict__ W1, const float* __restrict__ b1,
                             const float* __restrict__ W2, const float* __restrict__ b2,
                             const float* __restrict__ W3, const float* __restrict__ b3,
                             const float* __restrict__ W4, const float* __restrict__ b4,
                             const float* __restrict__ W5, const float* __restrict__ scales,
                             char* __restrict__ ws) {
  const int sub = blockIdx.x;
  const int tid = threadIdx.x;
  char* dst = ws + sub * SUBSZ;
  const float s0 = TWOLOG2E * scales[sub * 4 + 0];
  const float s1 = TWOLOG2E * scales[sub * 4 + 1];
  const float s2 = TWOLOG2E * scales[sub * 4 + 2];
  const float s3 = TWOLOG2E * scales[sub * 4 + 3];
#pragma unroll
  for (int l = 0; l < 3; ++l) {
    const float* src = (l == 0) ? (W2 + sub * 4096) : (l == 1) ? (W3 + sub * 4096) : (W4 + sub * 4096);
    const float sc   = (l == 0) ? s1 : (l == 1) ? s2 : s3;
    __hip_bfloat16* d = (__hip_bfloat16*)(dst + OFF_W + l * 8192);
    for (int idx = tid; idx < 4096; idx += 256) {
      int row = idx >> 6, col = idx & 63;
      int de = row * 64 + (col ^ ((row & 7) << 3));   // XOR swizzle (16B granules)
      d[de] = __float2bfloat16(sc * src[idx]);
    }
  }
  { // W1pad [64][16]
    __hip_bfloat16* d = (__hip_bfloat16*)(dst + OFF_W1);
    for (int idx = tid; idx < 1024; idx += 256) {
      int row = idx >> 4, kc = idx & 15;
      float v = 0.f;
      if (kc < 3)       v = s0 * W1[sub * 192 + row * 3 + kc];
      else if (kc == 3) v = s0 * b1[sub * 64 + row];
      d[idx] = __float2bfloat16(v);
    }
  }
  if (tid < 64) {
    ((__hip_bfloat16*)(dst + OFF_W5))[tid] = __float2bfloat16(W5[sub * 64 + tid]);
    ((float*)(dst + OFF_B))[tid]        = s1 * b2[sub * 64 + tid];
    ((float*)(dst + OFF_B + 256))[tid]  = s2 * b3[sub * 64 + tid];
    ((float*)(dst + OFF_B + 512))[tid]  = s3 * b4[sub * 64 + tid];
  }
}

__global__ __launch_bounds__(256) void pinn_main(
    const float* __restrict__ X, const float* __restrict__ T,
    const char* __restrict__ ws, const float* __restrict__ centers,
    const float* __restrict__ lgam, const float* __restrict__ b5,
    float* __restrict__ out) {
  __shared__ __align__(16) char smem[SUBSZ];
  const int tid  = threadIdx.x;
  const int lane = tid & 63;
  const int wid  = tid >> 6;
  const int g    = lane >> 5;
  const int lpt  = lane & 31;
  const int p    = blockIdx.x * 128 + wid * 32 + lpt;

  const float x  = X[p];
  const float tt = T[p];
  float rr = x * 0.5f;
  rr = rr - floorf(rr);                                 // revolutions for v_sin/v_cos
  const float cpx = __builtin_amdgcn_cosf(rr);          // cos(pi*x)
  const float spx = __builtin_amdgcn_sinf(rr);          // sin(pi*x)
  const float u0  = x * x * cpx;
  const float thT = fast_tanh(tt);

  // max over gating logits (stability; gamma=e^3~20 => raw exp underflows)
  float m = -1e30f;
#pragma unroll
  for (int i = 0; i < 8; ++i) {
    float gx = __builtin_amdgcn_exp2f(lgam[2 * i] * LOG2E);
    float gt = __builtin_amdgcn_exp2f(lgam[2 * i + 1] * LOG2E);
    float dx = x - centers[2 * i], dt = tt - centers[2 * i + 1];
    float lg = -(gx * dx * dx + gt * dt * dt);
    m = fmaxf(m, lg);
  }

  // layer-1 B fragment: act0 = [cos, sin, t, 1, 0...] ; only k<4 (half g=0) nonzero
  unsigned b00 = packbf(cpx, spx);
  unsigned b01 = packbf(tt, 1.0f);
  if (g) { b00 = 0u; b01 = 0u; }

  float uacc = 0.f, S = 0.f;

  for (int sub = 0; sub < KSUB; ++sub) {
    __syncthreads();
    const char* gb = ws + sub * SUBSZ;
    for (int ch = wid; ch < SUBSZ / 1024; ch += 4) {    // 27 KB blob -> LDS
      *(f32x4*)(smem + ch * 1024 + lane * 16) = *(const f32x4*)(gb + ch * 1024 + lane * 16);
    }
    __syncthreads();

    // gating weight for this subnet
    float gx = __builtin_amdgcn_exp2f(lgam[2 * sub] * LOG2E);
    float gt = __builtin_amdgcn_exp2f(lgam[2 * sub + 1] * LOG2E);
    float dx = x - centers[2 * sub], dtt = tt - centers[2 * sub + 1];
    float lg = -(gx * dx * dx + gt * dtt * dtt);
    float ei = __builtin_amdgcn_exp2f((lg - m) * LOG2E);

    // ---- layer 1 (K=16 padded, bias folded into col 3) ----
    f32x16 acc0, acc1;
#pragma unroll
    for (int r = 0; r < 16; ++r) { acc0[r] = 0.f; acc1[r] = 0.f; }
    s16x8 a0 = *(const s16x8*)(smem + OFF_W1 + lpt * 32 + g * 16);
    s16x8 a1 = *(const s16x8*)(smem + OFF_W1 + (32 + lpt) * 32 + g * 16);
    u32x4 blv; blv[0] = b00; blv[1] = b01; blv[2] = 0u; blv[3] = 0u;
    s16x8 bl1 = __builtin_bit_cast(s16x8, blv);
    acc0 = mfma_bf16(a0, bl1, acc0);
    acc1 = mfma_bf16(a1, bl1, acc1);
    unsigned Bu[16];
    epilogue(acc0, acc1, Bu);

    // ---- hidden layers 2..4 ----
    for (int l = 0; l < 3; ++l) {
      const float* bias = (const float*)(smem + OFF_B + l * 256);
#pragma unroll
      for (int rq = 0; rq < 4; ++rq) {                  // acc init = scaled bias
        f32x4 bv0 = *(const f32x4*)(bias + 8 * rq + 4 * g);
        f32x4 bv1 = *(const f32x4*)(bias + 32 + 8 * rq + 4 * g);
#pragma unroll
        for (int rr2 = 0; rr2 < 4; ++rr2) { acc0[4 * rq + rr2] = bv0[rr2]; acc1[4 * rq + rr2] = bv1[rr2]; }
      }
      const char* wbase = smem + OFF_W + l * 8192;
#pragma unroll
      for (int kt = 0; kt < 4; ++kt) {
        const int coff = ((16 * kt + 8 * g) * 2) ^ ((lpt & 7) << 4);  // match prep swizzle
        s16x8 wa0 = *(const s16x8*)(wbase + lpt * 128 + coff);
        s16x8 wa1 = *(const s16x8*)(wbase + (32 + lpt) * 128 + coff);
        u32x4 bb; bb[0] = Bu[kt * 4]; bb[1] = Bu[kt * 4 + 1]; bb[2] = Bu[kt * 4 + 2]; bb[3] = Bu[kt * 4 + 3];
        s16x8 bf = __builtin_bit_cast(s16x8, bb);
        acc0 = mfma_bf16(wa0, bf, acc0);
        acc1 = mfma_bf16(wa1, bf, acc1);
      }
      epilogue(acc0, acc1, Bu);
    }

    // ---- layer 5 via MFMA: broadcast W5 into every A row -> every C element = o+b5.
    // (C row j only reads A row j; all A rows identical => all acc5 regs equal.)
    const float b5s = b5[sub];
    f32x16 acc5;
#pragma unroll
    for (int r = 0; r < 16; ++r) acc5[r] = b5s;
#pragma unroll
    for (int kt = 0; kt < 4; ++kt) {
      s16x8 w5f = *(const s16x8*)(smem + OFF_W5 + (kt * 16 + 8 * g) * 2);
      u32x4 bb; bb[0] = Bu[kt * 4]; bb[1] = Bu[kt * 4 + 1]; bb[2] = Bu[kt * 4 + 2]; bb[3] = Bu[kt * 4 + 3];
      s16x8 bf = __builtin_bit_cast(s16x8, bb);
      acc5 = mfma_bf16(w5f, bf, acc5);
    }
    uacc = __builtin_fmaf(ei, acc5[0], uacc);
    S += ei;
  }

  float u = uacc * __builtin_amdgcn_rcpf(S);
  if (lane < 32) out[p] = thT * u + u0;
}

extern "C" void kernel_launch(void* const* d_in, const int* in_sizes, int n_in,
                              void* d_out, int out_size, void* d_ws, size_t ws_size,
                              hipStream_t stream) {
  const float* X   = (const float*)d_in[0];
  const float* T   = (const float*)d_in[1];
  const float* W1  = (const float*)d_in[2];
  const float* b1  = (const float*)d_in[3];
  const float* W2  = (const float*)d_in[4];
  const float* b2  = (const float*)d_in[5];
  const float* W3  = (const float*)d_in[6];
  const float* b3  = (const float*)d_in[7];
  const float* W4  = (const float*)d_in[8];
  const float* b4  = (const float*)d_in[9];
  const float* W5  = (const float*)d_in[10];
  const float* b5  = (const float*)d_in[11];
  const float* sc  = (const float*)d_in[12];
  const float* cen = (const float*)d_in[13];
  const float* lg  = (const float*)d_in[14];
  float* out = (float*)d_out;
  char*  ws  = (char*)d_ws;
  const int n = in_sizes[0];

  prep_weights<<<KSUB, 256, 0, stream>>>(W1, b1, W2, b2, W3, b3, W4, b4, W5, sc, ws);
  pinn_main<<<n / 128, 256, 0, stream>>>(X, T, ws, cen, lg, b5, out);
}

// Round 7
// 326.901 us; speedup vs baseline: 2.4164x; 1.9798x over previous
//
#include <hip/hip_runtime.h>
#include <hip/hip_bf16.h>
#include <stdint.h>

typedef __attribute__((ext_vector_type(8)))  short    s16x8;
typedef __attribute__((ext_vector_type(16))) float    f32x16;
typedef __attribute__((ext_vector_type(4)))  float    f32x4;
typedef __attribute__((ext_vector_type(4)))  unsigned u32x4;

#define KSUB 8
// per-subnet ws blob (bytes):
//   0      W2' bf16 [64][64]  (scale*2log2e folded, XOR-swizzled)   8192
//   8192   W3'                                                      8192
//   16384  W4'                                                      8192
//   24576  W1pad bf16 [64][16] (cols 0..2 = s0'*W1, col3 = s0'*b1)  2048
//   26624  W5 bf16 [64]                                             128
//   26752  b2' f32[64]; 27008 b3'; 27264 b4'  (all *2log2e*s)       768
//   27520  pad                                                      128
#define SUBSZ  27648
#define OFF_W  0
#define OFF_W1 24576
#define OFF_W5 26624
#define OFF_B  26752

// ws layout: [0, SUBSZ*8) weights; counts at WS_CNT (32B); buckets at WS_BKT (8*n*4B)
#define WS_CNT (SUBSZ * KSUB)
#define WS_BKT (WS_CNT + 256)

#define LOG2E 1.4426950408889634f
#define TWOLOG2E 2.885390081777927f   // 2/ln2, folded into scales so MFMA acc = exp2 arg
#define TAU 5e-4f                     // gating weight threshold; skip error <= ~7*TAU*|o|

__device__ __forceinline__ float fast_tanh(float z) {
  float e = __builtin_amdgcn_exp2f(z * TWOLOG2E);
  return __builtin_fmaf(-2.0f, __builtin_amdgcn_rcpf(e + 1.0f), 1.0f);
}
__device__ __forceinline__ float tanh_pre(float zeta) {   // zeta = 2*log2e*z prefolded
  float e = __builtin_amdgcn_exp2f(zeta);
  return __builtin_fmaf(-2.0f, __builtin_amdgcn_rcpf(e + 1.0f), 1.0f);
}

// pack two f32 -> bf16x2 with round-half-up: +0x8000 then one v_perm_b32.
__device__ __forceinline__ unsigned packbf(float lo, float hi) {
  unsigned ul = __builtin_bit_cast(unsigned, lo) + 0x8000u;
  unsigned uh = __builtin_bit_cast(unsigned, hi) + 0x8000u;
  return __builtin_amdgcn_perm(uh, ul, 0x07060302u);
}

__device__ __forceinline__ f32x16 mfma_bf16(s16x8 a, s16x8 b, f32x16 c) {
  return __builtin_amdgcn_mfma_f32_32x32x16_bf16(a, b, c, 0, 0, 0);
}

// C layout (32x32): col = lane&31 (=point), row j = (r&3)+8*(r>>2)+4*(lane>>5).
__device__ __forceinline__ void epilogue(const f32x16& acc0, const f32x16& acc1,
                                         unsigned Bu[16]) {
#pragma unroll
  for (int kt = 0; kt < 4; ++kt) {
#pragma unroll
    for (int qq = 0; qq < 2; ++qq) {
      const int ra = ((2 * kt) & 3) * 4 + 2 * qq;
      const int rb = ((2 * kt + 1) & 3) * 4 + 2 * qq;
      float a0v, a1v, b0v, b1v;
      if (kt < 2) { a0v = acc0[ra]; a1v = acc0[ra + 1]; b0v = acc0[rb]; b1v = acc0[rb + 1]; }
      else        { a0v = acc1[ra]; a1v = acc1[ra + 1]; b0v = acc1[rb]; b1v = acc1[rb + 1]; }
      unsigned P0 = packbf(tanh_pre(a0v), tanh_pre(a1v));
      unsigned P1 = packbf(tanh_pre(b0v), tanh_pre(b1v));
      auto pr = __builtin_amdgcn_permlane32_swap(P0, P1, false, false);
      Bu[kt * 4 + qq]     = pr[0];
      Bu[kt * 4 + qq + 2] = pr[1];
    }
  }
}

__global__ void prep_weights(const float* __restrict__ W1, const float* __restrict__ b1,
                             const float* __restrict__ W2, const float* __restrict__ b2,
                             const float* __restrict__ W3, const float* __restrict__ b3,
                             const float* __restrict__ W4, const float* __restrict__ b4,
                             const float* __restrict__ W5, const float* __restrict__ scales,
                             char* __restrict__ ws) {
  const int sub = blockIdx.x;
  const int tid = threadIdx.x;
  char* dst = ws + sub * SUBSZ;
  const float s0 = TWOLOG2E * scales[sub * 4 + 0];
  const float s1 = TWOLOG2E * scales[sub * 4 + 1];
  const float s2 = TWOLOG2E * scales[sub * 4 + 2];
  const float s3 = TWOLOG2E * scales[sub * 4 + 3];
#pragma unroll
  for (int l = 0; l < 3; ++l) {
    const float* src = (l == 0) ? (W2 + sub * 4096) : (l == 1) ? (W3 + sub * 4096) : (W4 + sub * 4096);
    const float sc   = (l == 0) ? s1 : (l == 1) ? s2 : s3;
    __hip_bfloat16* d = (__hip_bfloat16*)(dst + OFF_W + l * 8192);
    for (int idx = tid; idx < 4096; idx += 256) {
      int row = idx >> 6, col = idx & 63;
      int de = row * 64 + (col ^ ((row & 7) << 3));   // XOR swizzle (16B granules)
      d[de] = __float2bfloat16(sc * src[idx]);
    }
  }
  {
    __hip_bfloat16* d = (__hip_bfloat16*)(dst + OFF_W1);
    for (int idx = tid; idx < 1024; idx += 256) {
      int row = idx >> 4, kc = idx & 15;
      float v = 0.f;
      if (kc < 3)       v = s0 * W1[sub * 192 + row * 3 + kc];
      else if (kc == 3) v = s0 * b1[sub * 64 + row];
      d[idx] = __float2bfloat16(v);
    }
  }
  if (tid < 64) {
    ((__hip_bfloat16*)(dst + OFF_W5))[tid] = __float2bfloat16(W5[sub * 64 + tid]);
    ((float*)(dst + OFF_B))[tid]        = s1 * b2[sub * 64 + tid];
    ((float*)(dst + OFF_B + 256))[tid]  = s2 * b3[sub * 64 + tid];
    ((float*)(dst + OFF_B + 512))[tid]  = s3 * b4[sub * 64 + tid];
  }
}

// ---------- stage A: gating + bucket fill ----------
__global__ __launch_bounds__(256) void gate_bucket(
    const float* __restrict__ X, const float* __restrict__ T,
    const float* __restrict__ centers, const float* __restrict__ lgam,
    unsigned* __restrict__ counts, unsigned* __restrict__ buckets, int n) {
  const int tid  = threadIdx.x;
  const int lane = tid & 63;
  const int wid  = tid >> 6;
  const int p    = blockIdx.x * 256 + tid;
  const float x  = X[p];
  const float tt = T[p];

  float lgv[8];                       // static-index only (fully unrolled)
  float m = -1e30f;
#pragma unroll
  for (int i = 0; i < 8; ++i) {
    float gx = __builtin_amdgcn_exp2f(lgam[2 * i] * LOG2E);
    float gt = __builtin_amdgcn_exp2f(lgam[2 * i + 1] * LOG2E);
    float dx = x - centers[2 * i], dt = tt - centers[2 * i + 1];
    float lg = -(gx * dx * dx + gt * dt * dt);
    lgv[i] = lg;
    m = fmaxf(m, lg);
  }
  float ev[8]; float S = 0.f;
#pragma unroll
  for (int i = 0; i < 8; ++i) { ev[i] = __builtin_amdgcn_exp2f((lgv[i] - m) * LOG2E); S += ev[i]; }
  const float thr = TAU * S;
  unsigned mask = 0;
#pragma unroll
  for (int i = 0; i < 8; ++i) mask |= (ev[i] > thr) ? (1u << i) : 0u;

  __shared__ unsigned wcnt[8][4];
  __shared__ unsigned sbase[8];
#pragma unroll
  for (int i = 0; i < 8; ++i) {
    unsigned long long b = __ballot((mask >> i) & 1u);
    if (lane == 0) wcnt[i][wid] = (unsigned)__popcll(b);
  }
  __syncthreads();
  if (tid < 8) {
    unsigned tot = wcnt[tid][0] + wcnt[tid][1] + wcnt[tid][2] + wcnt[tid][3];
    sbase[tid] = atomicAdd(&counts[tid], tot);
  }
  __syncthreads();
#pragma unroll
  for (int i = 0; i < 8; ++i) {
    unsigned long long b = __ballot((mask >> i) & 1u);
    if ((mask >> i) & 1u) {
      unsigned pre = __builtin_amdgcn_mbcnt_hi((unsigned)(b >> 32),
                      __builtin_amdgcn_mbcnt_lo((unsigned)b, 0u));
      unsigned wpre = 0;
#pragma unroll
      for (int w = 0; w < 4; ++w) if (w < wid) wpre += wcnt[i][w];
      buckets[(size_t)i * n + sbase[i] + wpre + pre] = (unsigned)p;
    }
  }
}

// ---------- stage B: per-subnet evaluation over bucketed points ----------
__global__ __launch_bounds__(256) void pinn_eval(
    const float* __restrict__ X, const float* __restrict__ T,
    const char* __restrict__ ws, const float* __restrict__ centers,
    const float* __restrict__ lgam, const float* __restrict__ b5,
    const unsigned* __restrict__ counts, const unsigned* __restrict__ buckets,
    float* __restrict__ out, int n) {
  const int sub = blockIdx.y;
  const unsigned cnt = counts[sub];
  if (blockIdx.x * 128u >= cnt) return;          // uniform early-exit before any barrier

  __shared__ __align__(16) char smem[SUBSZ];
  const int tid  = threadIdx.x;
  const int lane = tid & 63;
  const int wid  = tid >> 6;
  const int g    = lane >> 5;
  const int lpt  = lane & 31;

  // stage this subnet's 27KB blob once
  const char* gb = ws + sub * SUBSZ;
  for (int ch = wid; ch < SUBSZ / 1024; ch += 4) {
    *(f32x4*)(smem + ch * 1024 + lane * 16) = *(const f32x4*)(gb + ch * 1024 + lane * 16);
  }

  const unsigned j = blockIdx.x * 128u + wid * 32u + (unsigned)lpt;
  const bool valid = j < cnt;
  const unsigned jj = valid ? j : (cnt - 1);
  const unsigned pidx = buckets[(size_t)sub * n + jj];
  const float x  = X[pidx];
  const float tt = T[pidx];

  // gating weight w_sub = exp(lg_sub - m)/S  (all 8 logits, exact softmax)
  float lgv[8]; float m = -1e30f;
#pragma unroll
  for (int i = 0; i < 8; ++i) {
    float gx = __builtin_amdgcn_exp2f(lgam[2 * i] * LOG2E);
    float gt = __builtin_amdgcn_exp2f(lgam[2 * i + 1] * LOG2E);
    float dx = x - centers[2 * i], dt = tt - centers[2 * i + 1];
    float lg = -(gx * dx * dx + gt * dt * dt);
    lgv[i] = lg;
    m = fmaxf(m, lg);
  }
  float S = 0.f, esub = 0.f;
#pragma unroll
  for (int i = 0; i < 8; ++i) {
    float e = __builtin_amdgcn_exp2f((lgv[i] - m) * LOG2E);
    S += e;
    esub = (i == sub) ? e : esub;                // no runtime array index
  }
  const float wsub = esub * __builtin_amdgcn_rcpf(S);

  // layer-1 B fragment: [cos, sin, t, 1] in k<4 (g=0 half only)
  float rr = x * 0.5f;
  rr = rr - floorf(rr);
  const float cpx = __builtin_amdgcn_cosf(rr);
  const float spx = __builtin_amdgcn_sinf(rr);
  unsigned b00 = packbf(cpx, spx);
  unsigned b01 = packbf(tt, 1.0f);
  if (g) { b00 = 0u; b01 = 0u; }

  __syncthreads();                               // weights staged

  // ---- layer 1 ----
  f32x16 acc0, acc1;
#pragma unroll
  for (int r = 0; r < 16; ++r) { acc0[r] = 0.f; acc1[r] = 0.f; }
  s16x8 a0 = *(const s16x8*)(smem + OFF_W1 + lpt * 32 + g * 16);
  s16x8 a1 = *(const s16x8*)(smem + OFF_W1 + (32 + lpt) * 32 + g * 16);
  u32x4 blv; blv[0] = b00; blv[1] = b01; blv[2] = 0u; blv[3] = 0u;
  s16x8 bl1 = __builtin_bit_cast(s16x8, blv);
  acc0 = mfma_bf16(a0, bl1, acc0);
  acc1 = mfma_bf16(a1, bl1, acc1);
  unsigned Bu[16];
  epilogue(acc0, acc1, Bu);

  // ---- hidden layers 2..4 ----
  for (int l = 0; l < 3; ++l) {
    const float* bias = (const float*)(smem + OFF_B + l * 256);
#pragma unroll
    for (int rq = 0; rq < 4; ++rq) {
      f32x4 bv0 = *(const f32x4*)(bias + 8 * rq + 4 * g);
      f32x4 bv1 = *(const f32x4*)(bias + 32 + 8 * rq + 4 * g);
#pragma unroll
      for (int rr2 = 0; rr2 < 4; ++rr2) { acc0[4 * rq + rr2] = bv0[rr2]; acc1[4 * rq + rr2] = bv1[rr2]; }
    }
    const char* wbase = smem + OFF_W + l * 8192;
#pragma unroll
    for (int kt = 0; kt < 4; ++kt) {
      const int coff = ((16 * kt + 8 * g) * 2) ^ ((lpt & 7) << 4);
      s16x8 wa0 = *(const s16x8*)(wbase + lpt * 128 + coff);
      s16x8 wa1 = *(const s16x8*)(wbase + (32 + lpt) * 128 + coff);
      u32x4 bb; bb[0] = Bu[kt * 4]; bb[1] = Bu[kt * 4 + 1]; bb[2] = Bu[kt * 4 + 2]; bb[3] = Bu[kt * 4 + 3];
      s16x8 bf = __builtin_bit_cast(s16x8, bb);
      acc0 = mfma_bf16(wa0, bf, acc0);
      acc1 = mfma_bf16(wa1, bf, acc1);
    }
    epilogue(acc0, acc1, Bu);
  }

  // ---- layer 5 via broadcast-A MFMA: every acc element = o + b5 ----
  const float b5s = b5[sub];
  f32x16 acc5;
#pragma unroll
  for (int r = 0; r < 16; ++r) acc5[r] = b5s;
#pragma unroll
  for (int kt = 0; kt < 4; ++kt) {
    s16x8 w5f = *(const s16x8*)(smem + OFF_W5 + (kt * 16 + 8 * g) * 2);
    u32x4 bb; bb[0] = Bu[kt * 4]; bb[1] = Bu[kt * 4 + 1]; bb[2] = Bu[kt * 4 + 2]; bb[3] = Bu[kt * 4 + 3];
    s16x8 bf = __builtin_bit_cast(s16x8, bb);
    acc5 = mfma_bf16(w5f, bf, acc5);
  }

  if ((lane < 32) && valid) atomicAdd(&out[pidx], wsub * acc5[0]);
}

// ---------- stage C: finalize u = tanh(t)*sum + x^2 cos(pi x) ----------
__global__ __launch_bounds__(256) void finalize(
    const float* __restrict__ X, const float* __restrict__ T,
    float* __restrict__ out) {
  const int p = blockIdx.x * 256 + threadIdx.x;
  const float x  = X[p];
  const float tt = T[p];
  float rr = x * 0.5f;
  rr = rr - floorf(rr);
  const float cpx = __builtin_amdgcn_cosf(rr);
  const float u0  = x * x * cpx;
  out[p] = fast_tanh(tt) * out[p] + u0;
}

// ---------- dense fallback (measured R6 path) ----------
__global__ __launch_bounds__(256) void pinn_main(
    const float* __restrict__ X, const float* __restrict__ T,
    const char* __restrict__ ws, const float* __restrict__ centers,
    const float* __restrict__ lgam, const float* __restrict__ b5,
    float* __restrict__ out) {
  __shared__ __align__(16) char smem[SUBSZ];
  const int tid  = threadIdx.x;
  const int lane = tid & 63;
  const int wid  = tid >> 6;
  const int g    = lane >> 5;
  const int lpt  = lane & 31;
  const int p    = blockIdx.x * 128 + wid * 32 + lpt;

  const float x  = X[p];
  const float tt = T[p];
  float rr = x * 0.5f;
  rr = rr - floorf(rr);
  const float cpx = __builtin_amdgcn_cosf(rr);
  const float spx = __builtin_amdgcn_sinf(rr);
  const float u0  = x * x * cpx;
  const float thT = fast_tanh(tt);

  float m = -1e30f;
#pragma unroll
  for (int i = 0; i < 8; ++i) {
    float gx = __builtin_amdgcn_exp2f(lgam[2 * i] * LOG2E);
    float gt = __builtin_amdgcn_exp2f(lgam[2 * i + 1] * LOG2E);
    float dx = x - centers[2 * i], dt = tt - centers[2 * i + 1];
    float lg = -(gx * dx * dx + gt * dt * dt);
    m = fmaxf(m, lg);
  }

  unsigned b00 = packbf(cpx, spx);
  unsigned b01 = packbf(tt, 1.0f);
  if (g) { b00 = 0u; b01 = 0u; }

  float uacc = 0.f, S = 0.f;

  for (int sub = 0; sub < KSUB; ++sub) {
    __syncthreads();
    const char* gb = ws + sub * SUBSZ;
    for (int ch = wid; ch < SUBSZ / 1024; ch += 4) {
      *(f32x4*)(smem + ch * 1024 + lane * 16) = *(const f32x4*)(gb + ch * 1024 + lane * 16);
    }
    __syncthreads();

    float gx = __builtin_amdgcn_exp2f(lgam[2 * sub] * LOG2E);
    float gt = __builtin_amdgcn_exp2f(lgam[2 * sub + 1] * LOG2E);
    float dx = x - centers[2 * sub], dtt = tt - centers[2 * sub + 1];
    float lg = -(gx * dx * dx + gt * dtt * dtt);
    float ei = __builtin_amdgcn_exp2f((lg - m) * LOG2E);

    f32x16 acc0, acc1;
#pragma unroll
    for (int r = 0; r < 16; ++r) { acc0[r] = 0.f; acc1[r] = 0.f; }
    s16x8 a0 = *(const s16x8*)(smem + OFF_W1 + lpt * 32 + g * 16);
    s16x8 a1 = *(const s16x8*)(smem + OFF_W1 + (32 + lpt) * 32 + g * 16);
    u32x4 blv; blv[0] = b00; blv[1] = b01; blv[2] = 0u; blv[3] = 0u;
    s16x8 bl1 = __builtin_bit_cast(s16x8, blv);
    acc0 = mfma_bf16(a0, bl1, acc0);
    acc1 = mfma_bf16(a1, bl1, acc1);
    unsigned Bu[16];
    epilogue(acc0, acc1, Bu);

    for (int l = 0; l < 3; ++l) {
      const float* bias = (const float*)(smem + OFF_B + l * 256);
#pragma unroll
      for (int rq = 0; rq < 4; ++rq) {
        f32x4 bv0 = *(const f32x4*)(bias + 8 * rq + 4 * g);
        f32x4 bv1 = *(const f32x4*)(bias + 32 + 8 * rq + 4 * g);
#pragma unroll
        for (int rr2 = 0; rr2 < 4; ++rr2) { acc0[4 * rq + rr2] = bv0[rr2]; acc1[4 * rq + rr2] = bv1[rr2]; }
      }
      const char* wbase = smem + OFF_W + l * 8192;
#pragma unroll
      for (int kt = 0; kt < 4; ++kt) {
        const int coff = ((16 * kt + 8 * g) * 2) ^ ((lpt & 7) << 4);
        s16x8 wa0 = *(const s16x8*)(wbase + lpt * 128 + coff);
        s16x8 wa1 = *(const s16x8*)(wbase + (32 + lpt) * 128 + coff);
        u32x4 bb; bb[0] = Bu[kt * 4]; bb[1] = Bu[kt * 4 + 1]; bb[2] = Bu[kt * 4 + 2]; bb[3] = Bu[kt * 4 + 3];
        s16x8 bf = __builtin_bit_cast(s16x8, bb);
        acc0 = mfma_bf16(wa0, bf, acc0);
        acc1 = mfma_bf16(wa1, bf, acc1);
      }
      epilogue(acc0, acc1, Bu);
    }

    const float b5s = b5[sub];
    f32x16 acc5;
#pragma unroll
    for (int r = 0; r < 16; ++r) acc5[r] = b5s;
#pragma unroll
    for (int kt = 0; kt < 4; ++kt) {
      s16x8 w5f = *(const s16x8*)(smem + OFF_W5 + (kt * 16 + 8 * g) * 2);
      u32x4 bb; bb[0] = Bu[kt * 4]; bb[1] = Bu[kt * 4 + 1]; bb[2] = Bu[kt * 4 + 2]; bb[3] = Bu[kt * 4 + 3];
      s16x8 bf = __builtin_bit_cast(s16x8, bb);
      acc5 = mfma_bf16(w5f, bf, acc5);
    }
    uacc = __builtin_fmaf(ei, acc5[0], uacc);
    S += ei;
  }

  float u = uacc * __builtin_amdgcn_rcpf(S);
  if (lane < 32) out[p] = thT * u + u0;
}

extern "C" void kernel_launch(void* const* d_in, const int* in_sizes, int n_in,
                              void* d_out, int out_size, void* d_ws, size_t ws_size,
                              hipStream_t stream) {
  const float* X   = (const float*)d_in[0];
  const float* T   = (const float*)d_in[1];
  const float* W1  = (const float*)d_in[2];
  const float* b1  = (const float*)d_in[3];
  const float* W2  = (const float*)d_in[4];
  const float* b2  = (const float*)d_in[5];
  const float* W3  = (const float*)d_in[6];
  const float* b3  = (const float*)d_in[7];
  const float* W4  = (const float*)d_in[8];
  const float* b4  = (const float*)d_in[9];
  const float* W5  = (const float*)d_in[10];
  const float* b5  = (const float*)d_in[11];
  const float* sc  = (const float*)d_in[12];
  const float* cen = (const float*)d_in[13];
  const float* lg  = (const float*)d_in[14];
  float* out = (float*)d_out;
  char*  ws  = (char*)d_ws;
  const int n = in_sizes[0];

  prep_weights<<<KSUB, 256, 0, stream>>>(W1, b1, W2, b2, W3, b3, W4, b4, W5, sc, ws);

  const size_t need = (size_t)WS_BKT + (size_t)KSUB * (size_t)n * 4ull;
  if (ws_size >= need) {
    unsigned* counts  = (unsigned*)(ws + WS_CNT);
    unsigned* buckets = (unsigned*)(ws + WS_BKT);
    hipMemsetAsync(counts, 0, 32, stream);
    hipMemsetAsync(out, 0, (size_t)n * 4, stream);
    gate_bucket<<<n / 256, 256, 0, stream>>>(X, T, cen, lg, counts, buckets, n);
    pinn_eval<<<dim3(n / 128, KSUB), 256, 0, stream>>>(X, T, ws, cen, lg, b5,
                                                       counts, buckets, out, n);
    finalize<<<n / 256, 256, 0, stream>>>(X, T, out);
  } else {
    pinn_main<<<n / 128, 256, 0, stream>>>(X, T, ws, cen, lg, b5, out);
  }
}

// Round 9
// 282.360 us; speedup vs baseline: 2.7976x; 1.1577x over previous
//
#include <hip/hip_runtime.h>
#include <hip/hip_bf16.h>
#include <stdint.h>

typedef __attribute__((ext_vector_type(8)))  short    s16x8;
typedef __attribute__((ext_vector_type(16))) float    f32x16;
typedef __attribute__((ext_vector_type(4)))  float    f32x4;
typedef __attribute__((ext_vector_type(4)))  unsigned u32x4;

#define KSUB 8
// per-subnet ws blob (bytes): see R6 comment (weights scale*2log2e-folded)
#define SUBSZ  27648
#define OFF_W  0
#define OFF_W1 24576
#define OFF_W5 26624
#define OFF_B  26752

// ws layout: [0, SUBSZ*8) weights; counts at WS_CNT (8 x 64B padded); buckets at WS_BKT
#define WS_CNT (SUBSZ * KSUB)
#define WS_BKT (WS_CNT + 512)

#define LOG2E 1.4426950408889634f
#define TWOLOG2E 2.885390081777927f
#define TAU 1e-3f    // skip threshold; skip error <= ~8*TAU*|o|max ~ 0.02

__device__ __forceinline__ float fast_tanh(float z) {
  float e = __builtin_amdgcn_exp2f(z * TWOLOG2E);
  return __builtin_fmaf(-2.0f, __builtin_amdgcn_rcpf(e + 1.0f), 1.0f);
}
__device__ __forceinline__ float tanh_pre(float zeta) {   // zeta = 2*log2e*z prefolded
  float e = __builtin_amdgcn_exp2f(zeta);
  return __builtin_fmaf(-2.0f, __builtin_amdgcn_rcpf(e + 1.0f), 1.0f);
}
__device__ __forceinline__ unsigned packbf(float lo, float hi) {
  unsigned ul = __builtin_bit_cast(unsigned, lo) + 0x8000u;
  unsigned uh = __builtin_bit_cast(unsigned, hi) + 0x8000u;
  return __builtin_amdgcn_perm(uh, ul, 0x07060302u);
}
__device__ __forceinline__ f32x16 mfma_bf16(s16x8 a, s16x8 b, f32x16 c) {
  return __builtin_amdgcn_mfma_f32_32x32x16_bf16(a, b, c, 0, 0, 0);
}

// C layout (32x32): col = lane&31 (=point), row j = (r&3)+8*(r>>2)+4*(lane>>5).
__device__ __forceinline__ void epilogue(const f32x16& acc0, const f32x16& acc1,
                                         unsigned Bu[16]) {
#pragma unroll
  for (int kt = 0; kt < 4; ++kt) {
#pragma unroll
    for (int qq = 0; qq < 2; ++qq) {
      const int ra = ((2 * kt) & 3) * 4 + 2 * qq;
      const int rb = ((2 * kt + 1) & 3) * 4 + 2 * qq;
      float a0v, a1v, b0v, b1v;
      if (kt < 2) { a0v = acc0[ra]; a1v = acc0[ra + 1]; b0v = acc0[rb]; b1v = acc0[rb + 1]; }
      else        { a0v = acc1[ra]; a1v = acc1[ra + 1]; b0v = acc1[rb]; b1v = acc1[rb + 1]; }
      unsigned P0 = packbf(tanh_pre(a0v), tanh_pre(a1v));
      unsigned P1 = packbf(tanh_pre(b0v), tanh_pre(b1v));
      auto pr = __builtin_amdgcn_permlane32_swap(P0, P1, false, false);
      Bu[kt * 4 + qq]     = pr[0];
      Bu[kt * 4 + qq + 2] = pr[1];
    }
  }
}

__global__ void prep_weights(const float* __restrict__ W1, const float* __restrict__ b1,
                             const float* __restrict__ W2, const float* __restrict__ b2,
                             const float* __restrict__ W3, const float* __restrict__ b3,
                             const float* __restrict__ W4, const float* __restrict__ b4,
                             const float* __restrict__ W5, const float* __restrict__ scales,
                             char* __restrict__ ws) {
  const int sub = blockIdx.x;
  const int tid = threadIdx.x;
  char* dst = ws + sub * SUBSZ;
  const float s0 = TWOLOG2E * scales[sub * 4 + 0];
  const float s1 = TWOLOG2E * scales[sub * 4 + 1];
  const float s2 = TWOLOG2E * scales[sub * 4 + 2];
  const float s3 = TWOLOG2E * scales[sub * 4 + 3];
#pragma unroll
  for (int l = 0; l < 3; ++l) {
    const float* src = (l == 0) ? (W2 + sub * 4096) : (l == 1) ? (W3 + sub * 4096) : (W4 + sub * 4096);
    const float sc   = (l == 0) ? s1 : (l == 1) ? s2 : s3;
    __hip_bfloat16* d = (__hip_bfloat16*)(dst + OFF_W + l * 8192);
    for (int idx = tid; idx < 4096; idx += 256) {
      int row = idx >> 6, col = idx & 63;
      int de = row * 64 + (col ^ ((row & 7) << 3));   // XOR swizzle (16B granules)
      d[de] = __float2bfloat16(sc * src[idx]);
    }
  }
  {
    __hip_bfloat16* d = (__hip_bfloat16*)(dst + OFF_W1);
    for (int idx = tid; idx < 1024; idx += 256) {
      int row = idx >> 4, kc = idx & 15;
      float v = 0.f;
      if (kc < 3)       v = s0 * W1[sub * 192 + row * 3 + kc];
      else if (kc == 3) v = s0 * b1[sub * 64 + row];
      d[idx] = __float2bfloat16(v);
    }
  }
  if (tid < 64) {
    ((__hip_bfloat16*)(dst + OFF_W5))[tid] = __float2bfloat16(W5[sub * 64 + tid]);
    ((float*)(dst + OFF_B))[tid]        = s1 * b2[sub * 64 + tid];
    ((float*)(dst + OFF_B + 256))[tid]  = s2 * b3[sub * 64 + tid];
    ((float*)(dst + OFF_B + 512))[tid]  = s3 * b4[sub * 64 + tid];
  }
}

// ---------- stage A: gating + bucket fill (2-pass, 1 global atomic/subnet/block) ----
#define GCHUNK 8
__global__ __launch_bounds__(256) void gate_bucket(
    const float* __restrict__ X, const float* __restrict__ T,
    const float* __restrict__ centers, const float* __restrict__ lgam,
    unsigned* __restrict__ counts, unsigned* __restrict__ buckets, int n) {
  __shared__ unsigned tot[8], cursor[8];
  const int tid  = threadIdx.x;
  const int lane = tid & 63;
  const int base = blockIdx.x * (256 * GCHUNK);
  if (tid < 8) tot[tid] = 0;
  __syncthreads();

  // pass 1: per-block totals per subnet
  for (int c = 0; c < GCHUNK; ++c) {
    const int p = base + c * 256 + tid;
    const float x = X[p], tt = T[p];
    float lgv[8]; float m = -1e30f;
#pragma unroll
    for (int i = 0; i < 8; ++i) {
      float gx = __builtin_amdgcn_exp2f(lgam[2 * i] * LOG2E);
      float gt = __builtin_amdgcn_exp2f(lgam[2 * i + 1] * LOG2E);
      float dx = x - centers[2 * i], dt = tt - centers[2 * i + 1];
      float lg = -(gx * dx * dx + gt * dt * dt);
      lgv[i] = lg; m = fmaxf(m, lg);
    }
    float S = 0.f; float ev[8];
#pragma unroll
    for (int i = 0; i < 8; ++i) { ev[i] = __builtin_amdgcn_exp2f((lgv[i] - m) * LOG2E); S += ev[i]; }
    const float thr = TAU * S;
#pragma unroll
    for (int i = 0; i < 8; ++i) {
      unsigned long long b = __ballot(ev[i] > thr);
      if (lane == 0) atomicAdd(&tot[i], (unsigned)__popcll(b));
    }
  }
  __syncthreads();
  if (tid < 8) cursor[tid] = atomicAdd(&counts[tid * 16], tot[tid]);  // 64B-padded counters
  __syncthreads();

  // pass 2: recompute gating, claim wave slots from LDS cursor, write entries
  for (int c = 0; c < GCHUNK; ++c) {
    const int p = base + c * 256 + tid;
    const float x = X[p], tt = T[p];
    float lgv[8]; float m = -1e30f;
#pragma unroll
    for (int i = 0; i < 8; ++i) {
      float gx = __builtin_amdgcn_exp2f(lgam[2 * i] * LOG2E);
      float gt = __builtin_amdgcn_exp2f(lgam[2 * i + 1] * LOG2E);
      float dx = x - centers[2 * i], dt = tt - centers[2 * i + 1];
      float lg = -(gx * dx * dx + gt * dt * dt);
      lgv[i] = lg; m = fmaxf(m, lg);
    }
    float S = 0.f; float ev[8];
#pragma unroll
    for (int i = 0; i < 8; ++i) { ev[i] = __builtin_amdgcn_exp2f((lgv[i] - m) * LOG2E); S += ev[i]; }
    const float thr = TAU * S;
    const float rS = __builtin_amdgcn_rcpf(S);
#pragma unroll
    for (int i = 0; i < 8; ++i) {
      unsigned long long b = __ballot(ev[i] > thr);
      unsigned cw = (unsigned)__popcll(b);
      unsigned wb = 0;
      if (lane == 0 && cw) wb = atomicAdd(&cursor[i], cw);
      wb = __shfl(wb, 0);
      if (ev[i] > thr) {
        unsigned pre = __builtin_amdgcn_mbcnt_hi((unsigned)(b >> 32),
                        __builtin_amdgcn_mbcnt_lo((unsigned)b, 0u));
        unsigned wq = (unsigned)(ev[i] * rS * 4095.f + 0.5f);   // 12-bit weight
        buckets[(size_t)i * n + wb + pre] = (wq << 20) | (unsigned)p;
      }
    }
  }
}

// ---------- stage B: per-subnet evaluation over bucketed points ----------
__global__ __launch_bounds__(256) void pinn_eval(
    const float* __restrict__ X, const float* __restrict__ T,
    const char* __restrict__ ws, const float* __restrict__ b5,
    const unsigned* __restrict__ counts, const unsigned* __restrict__ buckets,
    float* __restrict__ out, int n) {
  const int sub = blockIdx.y;
  const unsigned cnt = counts[sub * 16];
  if (blockIdx.x * 128u >= cnt) return;          // uniform early-exit before any barrier

  __shared__ __align__(16) char smem[SUBSZ];
  const int tid  = threadIdx.x;
  const int lane = tid & 63;
  const int wid  = tid >> 6;
  const int g    = lane >> 5;
  const int lpt  = lane & 31;

  const char* gb = ws + sub * SUBSZ;
  for (int ch = wid; ch < SUBSZ / 1024; ch += 4) {
    *(f32x4*)(smem + ch * 1024 + lane * 16) = *(const f32x4*)(gb + ch * 1024 + lane * 16);
  }

  const unsigned j = blockIdx.x * 128u + wid * 32u + (unsigned)lpt;
  const bool valid = j < cnt;
  const unsigned jj = valid ? j : (cnt - 1);
  const unsigned ent = buckets[(size_t)sub * n + jj];
  const unsigned pidx = ent & 0xFFFFFu;
  const float wsub = (float)(ent >> 20) * (1.0f / 4095.0f);
  const float x  = X[pidx];
  const float tt = T[pidx];

  float rr = x * 0.5f;
  rr = rr - floorf(rr);
  const float cpx = __builtin_amdgcn_cosf(rr);
  const float spx = __builtin_amdgcn_sinf(rr);
  unsigned b00 = packbf(cpx, spx);
  unsigned b01 = packbf(tt, 1.0f);
  if (g) { b00 = 0u; b01 = 0u; }

  __syncthreads();                               // weights staged

  f32x16 acc0, acc1;
#pragma unroll
  for (int r = 0; r < 16; ++r) { acc0[r] = 0.f; acc1[r] = 0.f; }
  s16x8 a0 = *(const s16x8*)(smem + OFF_W1 + lpt * 32 + g * 16);
  s16x8 a1 = *(const s16x8*)(smem + OFF_W1 + (32 + lpt) * 32 + g * 16);
  u32x4 blv; blv[0] = b00; blv[1] = b01; blv[2] = 0u; blv[3] = 0u;
  s16x8 bl1 = __builtin_bit_cast(s16x8, blv);
  acc0 = mfma_bf16(a0, bl1, acc0);
  acc1 = mfma_bf16(a1, bl1, acc1);
  unsigned Bu[16];
  epilogue(acc0, acc1, Bu);

  for (int l = 0; l < 3; ++l) {
    const float* bias = (const float*)(smem + OFF_B + l * 256);
#pragma unroll
    for (int rq = 0; rq < 4; ++rq) {
      f32x4 bv0 = *(const f32x4*)(bias + 8 * rq + 4 * g);
      f32x4 bv1 = *(const f32x4*)(bias + 32 + 8 * rq + 4 * g);
#pragma unroll
      for (int rr2 = 0; rr2 < 4; ++rr2) { acc0[4 * rq + rr2] = bv0[rr2]; acc1[4 * rq + rr2] = bv1[rr2]; }
    }
    const char* wbase = smem + OFF_W + l * 8192;
#pragma unroll
    for (int kt = 0; kt < 4; ++kt) {
      const int coff = ((16 * kt + 8 * g) * 2) ^ ((lpt & 7) << 4);
      s16x8 wa0 = *(const s16x8*)(wbase + lpt * 128 + coff);
      s16x8 wa1 = *(const s16x8*)(wbase + (32 + lpt) * 128 + coff);
      u32x4 bb; bb[0] = Bu[kt * 4]; bb[1] = Bu[kt * 4 + 1]; bb[2] = Bu[kt * 4 + 2]; bb[3] = Bu[kt * 4 + 3];
      s16x8 bf = __builtin_bit_cast(s16x8, bb);
      acc0 = mfma_bf16(wa0, bf, acc0);
      acc1 = mfma_bf16(wa1, bf, acc1);
    }
    epilogue(acc0, acc1, Bu);
  }

  const float b5s = b5[sub];
  f32x16 acc5;
#pragma unroll
  for (int r = 0; r < 16; ++r) acc5[r] = b5s;
#pragma unroll
  for (int kt = 0; kt < 4; ++kt) {
    s16x8 w5f = *(const s16x8*)(smem + OFF_W5 + (kt * 16 + 8 * g) * 2);
    u32x4 bb; bb[0] = Bu[kt * 4]; bb[1] = Bu[kt * 4 + 1]; bb[2] = Bu[kt * 4 + 2]; bb[3] = Bu[kt * 4 + 3];
    s16x8 bf = __builtin_bit_cast(s16x8, bb);
    acc5 = mfma_bf16(w5f, bf, acc5);
  }

  if ((lane < 32) && valid) atomicAdd(&out[pidx], wsub * acc5[0]);
}

// ---------- stage C: finalize u = tanh(t)*sum + x^2 cos(pi x) ----------
__global__ __launch_bounds__(256) void finalize(
    const float* __restrict__ X, const float* __restrict__ T,
    float* __restrict__ out) {
  const int p = blockIdx.x * 256 + threadIdx.x;
  const float x  = X[p];
  const float tt = T[p];
  float rr = x * 0.5f;
  rr = rr - floorf(rr);
  const float cpx = __builtin_amdgcn_cosf(rr);
  const float u0  = x * x * cpx;
  out[p] = fast_tanh(tt) * out[p] + u0;
}

// ---------- dense fallback (measured R6 path) ----------
__global__ __launch_bounds__(256) void pinn_main(
    const float* __restrict__ X, const float* __restrict__ T,
    const char* __restrict__ ws, const float* __restrict__ centers,
    const float* __restrict__ lgam, const float* __restrict__ b5,
    float* __restrict__ out) {
  __shared__ __align__(16) char smem[SUBSZ];
  const int tid  = threadIdx.x;
  const int lane = tid & 63;
  const int wid  = tid >> 6;
  const int g    = lane >> 5;
  const int lpt  = lane & 31;
  const int p    = blockIdx.x * 128 + wid * 32 + lpt;

  const float x  = X[p];
  const float tt = T[p];
  float rr = x * 0.5f;
  rr = rr - floorf(rr);
  const float cpx = __builtin_amdgcn_cosf(rr);
  const float spx = __builtin_amdgcn_sinf(rr);
  const float u0  = x * x * cpx;
  const float thT = fast_tanh(tt);

  float m = -1e30f;
#pragma unroll
  for (int i = 0; i < 8; ++i) {
    float gx = __builtin_amdgcn_exp2f(lgam[2 * i] * LOG2E);
    float gt = __builtin_amdgcn_exp2f(lgam[2 * i + 1] * LOG2E);
    float dx = x - centers[2 * i], dt = tt - centers[2 * i + 1];
    float lg = -(gx * dx * dx + gt * dt * dt);
    m = fmaxf(m, lg);
  }

  unsigned b00 = packbf(cpx, spx);
  unsigned b01 = packbf(tt, 1.0f);
  if (g) { b00 = 0u; b01 = 0u; }

  float uacc = 0.f, S = 0.f;

  for (int sub = 0; sub < KSUB; ++sub) {
    __syncthreads();
    const char* gb = ws + sub * SUBSZ;
    for (int ch = wid; ch < SUBSZ / 1024; ch += 4) {
      *(f32x4*)(smem + ch * 1024 + lane * 16) = *(const f32x4*)(gb + ch * 1024 + lane * 16);
    }
    __syncthreads();

    float gx = __builtin_amdgcn_exp2f(lgam[2 * sub] * LOG2E);
    float gt = __builtin_amdgcn_exp2f(lgam[2 * sub + 1] * LOG2E);
    float dx = x - centers[2 * sub], dtt = tt - centers[2 * sub + 1];
    float lg = -(gx * dx * dx + gt * dtt * dtt);
    float ei = __builtin_amdgcn_exp2f((lg - m) * LOG2E);

    f32x16 acc0, acc1;
#pragma unroll
    for (int r = 0; r < 16; ++r) { acc0[r] = 0.f; acc1[r] = 0.f; }
    s16x8 a0 = *(const s16x8*)(smem + OFF_W1 + lpt * 32 + g * 16);
    s16x8 a1 = *(const s16x8*)(smem + OFF_W1 + (32 + lpt) * 32 + g * 16);
    u32x4 blv; blv[0] = b00; blv[1] = b01; blv[2] = 0u; blv[3] = 0u;
    s16x8 bl1 = __builtin_bit_cast(s16x8, blv);
    acc0 = mfma_bf16(a0, bl1, acc0);
    acc1 = mfma_bf16(a1, bl1, acc1);
    unsigned Bu[16];
    epilogue(acc0, acc1, Bu);

    for (int l = 0; l < 3; ++l) {
      const float* bias = (const float*)(smem + OFF_B + l * 256);
#pragma unroll
      for (int rq = 0; rq < 4; ++rq) {
        f32x4 bv0 = *(const f32x4*)(bias + 8 * rq + 4 * g);
        f32x4 bv1 = *(const f32x4*)(bias + 32 + 8 * rq + 4 * g);
#pragma unroll
        for (int rr2 = 0; rr2 < 4; ++rr2) { acc0[4 * rq + rr2] = bv0[rr2]; acc1[4 * rq + rr2] = bv1[rr2]; }
      }
      const char* wbase = smem + OFF_W + l * 8192;
#pragma unroll
      for (int kt = 0; kt < 4; ++kt) {
        const int coff = ((16 * kt + 8 * g) * 2) ^ ((lpt & 7) << 4);
        s16x8 wa0 = *(const s16x8*)(wbase + lpt * 128 + coff);
        s16x8 wa1 = *(const s16x8*)(wbase + (32 + lpt) * 128 + coff);
        u32x4 bb; bb[0] = Bu[kt * 4]; bb[1] = Bu[kt * 4 + 1]; bb[2] = Bu[kt * 4 + 2]; bb[3] = Bu[kt * 4 + 3];
        s16x8 bf = __builtin_bit_cast(s16x8, bb);
        acc0 = mfma_bf16(wa0, bf, acc0);
        acc1 = mfma_bf16(wa1, bf, acc1);
      }
      epilogue(acc0, acc1, Bu);
    }

    const float b5s = b5[sub];
    f32x16 acc5;
#pragma unroll
    for (int r = 0; r < 16; ++r) acc5[r] = b5s;
#pragma unroll
    for (int kt = 0; kt < 4; ++kt) {
      s16x8 w5f = *(const s16x8*)(smem + OFF_W5 + (kt * 16 + 8 * g) * 2);
      u32x4 bb; bb[0] = Bu[kt * 4]; bb[1] = Bu[kt * 4 + 1]; bb[2] = Bu[kt * 4 + 2]; bb[3] = Bu[kt * 4 + 3];
      s16x8 bf = __builtin_bit_cast(s16x8, bb);
      acc5 = mfma_bf16(w5f, bf, acc5);
    }
    uacc = __builtin_fmaf(ei, acc5[0], uacc);
    S += ei;
  }

  float u = uacc * __builtin_amdgcn_rcpf(S);
  if (lane < 32) out[p] = thT * u + u0;
}

extern "C" void kernel_launch(void* const* d_in, const int* in_sizes, int n_in,
                              void* d_out, int out_size, void* d_ws, size_t ws_size,
                              hipStream_t stream) {
  const float* X   = (const float*)d_in[0];
  const float* T   = (const float*)d_in[1];
  const float* W1  = (const float*)d_in[2];
  const float* b1  = (const float*)d_in[3];
  const float* W2  = (const float*)d_in[4];
  const float* b2  = (const float*)d_in[5];
  const float* W3  = (const float*)d_in[6];
  const float* b3  = (const float*)d_in[7];
  const float* W4  = (const float*)d_in[8];
  const float* b4  = (const float*)d_in[9];
  const float* W5  = (const float*)d_in[10];
  const float* b5  = (const float*)d_in[11];
  const float* sc  = (const float*)d_in[12];
  const float* cen = (const float*)d_in[13];
  const float* lg  = (const float*)d_in[14];
  float* out = (float*)d_out;
  char*  ws  = (char*)d_ws;
  const int n = in_sizes[0];

  prep_weights<<<KSUB, 256, 0, stream>>>(W1, b1, W2, b2, W3, b3, W4, b4, W5, sc, ws);

  const size_t need = (size_t)WS_BKT + (size_t)KSUB * (size_t)n * 4ull;
  if (ws_size >= need) {
    unsigned* counts  = (unsigned*)(ws + WS_CNT);
    unsigned* buckets = (unsigned*)(ws + WS_BKT);
    hipMemsetAsync(counts, 0, 512, stream);
    hipMemsetAsync(out, 0, (size_t)n * 4, stream);
    gate_bucket<<<n / (256 * GCHUNK), 256, 0, stream>>>(X, T, cen, lg, counts, buckets, n);
    pinn_eval<<<dim3(n / 128, KSUB), 256, 0, stream>>>(X, T, ws, b5, counts, buckets, out, n);
    finalize<<<n / 256, 256, 0, stream>>>(X, T, out);
  } else {
    pinn_main<<<n / 128, 256, 0, stream>>>(X, T, ws, cen, lg, b5, out);
  }
}